// Round 4
// baseline (233.747 us; speedup 1.0000x reference)
//
#include <hip/hip_runtime.h>

// Problem constants (match reference)
#define Bq 8
#define Cq 128
#define Hq 128
#define Wq 256
#define Nq 1024
#define BN (Bq * Nq)
#define HWq (Hq * Wq)            // 32768 pixels per (b,c) plane
#define FBT_ELEMS ((size_t)Bq * Cq * HWq)   // 33,554,432 floats = 128 MiB

#define LOG_2PI 1.8378770664093453f
#define EPSq 1e-9f

// ---------------------------------------------------------------------------
// Pass 1: NCHW -> NHWC transpose, v2.
// Each block: ALL 128 channels x 128 pixels. Reads: 512B contiguous float4
// runs per channel row. Writes: ONE fully contiguous 64KB run per block
// (fixes the 256B-half-of-512B write pattern of v1, suspected 2x write loss).
// LDS: tile[pixel][channel] (64KB) with XOR swizzle on the channel-f4 index
// (slot = c4 ^ (p&31)) -> read-out ds_read_b128 is conflict-free.
// Grid: B * (HW/128) = 8 * 256 = 2048 blocks of 512 threads.
// ---------------------------------------------------------------------------
__global__ __launch_bounds__(512) void transpose_nchw_nhwc(
    const float* __restrict__ in, float* __restrict__ out)
{
    __shared__ float tile[128 * 128];    // [p][c-swizzled], 64 KiB
    const int blk = blockIdx.x;
    const int pt = blk & 255;            // pixel-chunk
    const int b  = blk >> 8;             // batch
    const int p0 = pt << 7;              // 128 pixels per chunk
    const int fx = threadIdx.x & 31;     // f4 index in pixel dim: px 4fx..4fx+3
    const int cr = threadIdx.x >> 5;     // 0..15

    const float* src = in + (size_t)b * Cq * HWq + p0;
    #pragma unroll
    for (int pass = 0; pass < 8; ++pass) {
        const int c = cr + (pass << 4);                  // channel row 0..127
        const float4 v = *(const float4*)(src + (size_t)c * HWq + 4 * fx);
        const int c4 = c >> 2, cl = c & 3;
        #pragma unroll
        for (int j = 0; j < 4; ++j) {
            const int p = 4 * fx + j;
            const float vj = j == 0 ? v.x : (j == 1 ? v.y : (j == 2 ? v.z : v.w));
            tile[p * 128 + ((c4 ^ (p & 31)) << 2) + cl] = vj;
        }
    }
    __syncthreads();
    float* dst = out + ((size_t)b * HWq + p0) * Cq;
    #pragma unroll
    for (int pass = 0; pass < 8; ++pass) {
        const int p = (threadIdx.x >> 5) + (pass << 4);  // pixel 0..127
        const int c4 = threadIdx.x & 31;                 // channel f4 group
        const float4 v = *(const float4*)(tile + p * 128 + ((c4 ^ (p & 31)) << 2));
        *(float4*)(dst + (size_t)p * Cq + 4 * c4) = v;   // fully contiguous 64KB/block
    }
}

// ---------------------------------------------------------------------------
// Pass 2: per-sample Gauss-Newton accumulation on NHWC data.
// 4 samples per 256-thread block; each sample owned by one 64-lane wave.
// Lane owns channels (2*lane, 2*lane+1) via float2 -> every stencil-point
// load is one contiguous 512B wave fetch. Pure wave reduction, no LDS.
// ---------------------------------------------------------------------------
__global__ __launch_bounds__(256) void gn_sample_nhwc(
    const float* __restrict__ fbT,
    const float* __restrict__ f_t,
    const float* __restrict__ ub,
    const float* __restrict__ noise,
    float* __restrict__ partials)
{
    const int n = (blockIdx.x << 2) + (threadIdx.x >> 6);  // sample in [0, B*N)
    const int b = n >> 10;             // n / N  (N = 1024)
    const int lane = threadIdx.x & 63;

    const float ubx = ub[2 * n];
    const float uby = ub[2 * n + 1];
    const float xsx = ubx + noise[2 * n];
    const float xsy = uby + noise[2 * n + 1];

    float x = fminf(fmaxf(xsx, 0.0f), (float)(Wq - 1));
    float y = fminf(fmaxf(xsy, 0.0f), (float)(Hq - 1));
    int x0 = (int)floorf(x); x0 = min(max(x0, 0), Wq - 2);
    int y0 = (int)floorf(y); y0 = min(max(y0, 0), Hq - 2);
    const int x1 = x0 + 1, y1 = y0 + 1;
    const float wx = x - (float)x0;
    const float wy = y - (float)y0;

    const int xlo0 = max(x0 - 1, 0);
    const int xhi1 = min(x1 + 1, Wq - 1);
    const int ylo0 = max(y0 - 1, 0);
    const int yhi1 = min(y1 + 1, Hq - 1);
    const float sx0 = 1.0f / (float)(x1 - xlo0);
    const float sx1 = 1.0f / (float)(xhi1 - x0);
    const float sy0 = 1.0f / (float)(y1 - ylo0);
    const float sy1 = 1.0f / (float)(yhi1 - y0);

    const size_t bb = (size_t)b * HWq;
    const int co = lane * 2;
    #define PT(yy, xx) (*(const float2*)(fbT + ((bb + (size_t)(yy) * Wq + (xx)) * Cq + co)))

    const float2 f_lo0 = PT(ylo0, x0), f_lo1 = PT(ylo0, x1);
    const float2 f0m = PT(y0, xlo0), f00 = PT(y0, x0), f01 = PT(y0, x1), f0p = PT(y0, xhi1);
    const float2 f1m = PT(y1, xlo0), f10 = PT(y1, x0), f11 = PT(y1, x1), f1p = PT(y1, xhi1);
    const float2 f_hi0 = PT(yhi1, x0), f_hi1 = PT(yhi1, x1);
    #undef PT

    const float2 ft = *(const float2*)(f_t + (size_t)n * Cq + co);

    const float w00 = (1.0f - wx) * (1.0f - wy);
    const float w01 = wx * (1.0f - wy);
    const float w10 = (1.0f - wx) * wy;
    const float w11 = wx * wy;

    float hxx = 0.0f, hxy = 0.0f, hyy = 0.0f, bx = 0.0f, by = 0.0f;
    #pragma unroll
    for (int k = 0; k < 2; ++k) {
        const float vlo0 = (k ? f_lo0.y : f_lo0.x), vlo1 = (k ? f_lo1.y : f_lo1.x);
        const float v0m = (k ? f0m.y : f0m.x), v00 = (k ? f00.y : f00.x);
        const float v01 = (k ? f01.y : f01.x), v0p = (k ? f0p.y : f0p.x);
        const float v1m = (k ? f1m.y : f1m.x), v10 = (k ? f10.y : f10.x);
        const float v11 = (k ? f11.y : f11.x), v1p = (k ? f1p.y : f1p.x);
        const float vhi0 = (k ? f_hi0.y : f_hi0.x), vhi1 = (k ? f_hi1.y : f_hi1.x);
        const float vt = (k ? ft.y : ft.x);

        const float gx00 = (v01 - v0m) * sx0;
        const float gx01 = (v0p - v00) * sx1;
        const float gx10 = (v11 - v1m) * sx0;
        const float gx11 = (v1p - v10) * sx1;
        const float gy00 = (v10 - vlo0) * sy0;
        const float gy01 = (v11 - vlo1) * sy0;
        const float gy10 = (vhi0 - v00) * sy1;
        const float gy11 = (vhi1 - v01) * sy1;

        const float fs = v00 * w00 + v01 * w01 + v10 * w10 + v11 * w11;
        const float Jx = gx00 * w00 + gx01 * w01 + gx10 * w10 + gx11 * w11;
        const float Jy = gy00 * w00 + gy01 * w01 + gy10 * w10 + gy11 * w11;
        const float r  = fs - vt;

        hxx += Jx * Jx;
        hxy += Jx * Jy;
        hyy += Jy * Jy;
        bx  += Jx * r;
        by  += Jy * r;
    }

    // 64-lane wave reduction (stays inside each wave; no LDS, no sync)
    #pragma unroll
    for (int off = 32; off > 0; off >>= 1) {
        hxx += __shfl_down(hxx, off);
        hxy += __shfl_down(hxy, off);
        hyy += __shfl_down(hyy, off);
        bx  += __shfl_down(bx, off);
        by  += __shfl_down(by, off);
    }

    if (lane == 0) {
        const float A  = hxx + EPSq;
        const float Bv = hxy;
        const float D  = hyy + EPSq;

        const float det = A * D - Bv * Bv;
        const float inv = 1.0f / det;
        const float hbx = ( D * bx - Bv * by) * inv;
        const float hby = (-Bv * bx + A * by) * inv;
        const float dx = ubx - (xsx - hbx);
        const float dy = uby - (xsy - hby);
        const float quad = A * dx * dx + 2.0f * Bv * dx * dy + D * dy * dy;

        const float detc = fmaxf(det, 1e-16f);
        partials[n]      = 0.5f * quad;     // e1 contribution
        partials[BN + n] = logf(detc);      // log det contribution
    }
}

// ---------------------------------------------------------------------------
// Single-block final reduction -> (e, e1, e2)
// ---------------------------------------------------------------------------
__global__ __launch_bounds__(1024) void gn_reduce_kernel(
    const float* __restrict__ partials, float* __restrict__ out)
{
    float s1 = 0.0f, s2 = 0.0f;
    for (int i = threadIdx.x; i < BN; i += 1024) {
        s1 += partials[i];
        s2 += partials[BN + i];
    }
    #pragma unroll
    for (int off = 32; off > 0; off >>= 1) {
        s1 += __shfl_down(s1, off);
        s2 += __shfl_down(s2, off);
    }
    __shared__ float l1[16], l2[16];
    const int w = threadIdx.x >> 6;
    if ((threadIdx.x & 63) == 0) { l1[w] = s1; l2[w] = s2; }
    __syncthreads();
    if (threadIdx.x == 0) {
        float e1 = 0.0f, sl = 0.0f;
        #pragma unroll
        for (int i = 0; i < 16; ++i) { e1 += l1[i]; sl += l2[i]; }
        const float e2 = (float)BN * LOG_2PI - 0.5f * sl;
        out[0] = e1 + (2.0f / 7.0f) * e2;  // e
        out[1] = e1;
        out[2] = e2;
    }
}

extern "C" void kernel_launch(void* const* d_in, const int* in_sizes, int n_in,
                              void* d_out, int out_size, void* d_ws, size_t ws_size,
                              hipStream_t stream) {
    const float* fb    = (const float*)d_in[0];
    const float* f_t   = (const float*)d_in[1];
    const float* ub    = (const float*)d_in[2];
    const float* noise = (const float*)d_in[3];
    float* out = (float*)d_out;
    float* wsf = (float*)d_ws;
    float* fbT      = wsf;                 // 128 MiB NHWC copy of fb
    float* partials = wsf + FBT_ELEMS;     // 2 * B*N floats

    transpose_nchw_nhwc<<<Bq * (HWq / 128), 512, 0, stream>>>(fb, fbT);
    gn_sample_nhwc<<<BN / 4, 256, 0, stream>>>(fbT, f_t, ub, noise, partials);
    gn_reduce_kernel<<<1, 1024, 0, stream>>>(partials, out);
}

// Round 5
// 212.515 us; speedup vs baseline: 1.0999x; 1.0999x over previous
//
#include <hip/hip_runtime.h>

// Problem constants (match reference)
#define Bq 8
#define Cq 128
#define Hq 128
#define Wq 256
#define Nq 1024
#define BN (Bq * Nq)
#define HWq (Hq * Wq)

#define LOG_2PI 1.8378770664093453f
#define EPSq 1e-9f

// Binned-gather configuration
#define NGRP 32            // y0 row-groups per batch (rows [4g, 4g+8))
#define NBINS (Bq * NGRP)  // 256 bins
#define BIN_CAP 1024       // worst-case samples per bin (physically <= 1024/batch)
#define CCH 8              // channels per chunk
#define NCHUNK (Cq / CCH)  // 16

// ws layout (in 4-byte units):
// [0, 256)            bin_count (int)
// [256, 256+256*1024) bin_samples (int)
// H_OFF..             partialsH: [NCHUNK][BN][5] float
// P2_OFF..            partials2: [2][BN] float
#define BS_OFF 256
#define H_OFF (BS_OFF + NBINS * BIN_CAP)
#define P2_OFF (H_OFF + NCHUNK * BN * 5)

// ---------------------------------------------------------------------------
// Kernel 0: zero the bin counters (avoids hipMemsetAsync questions in capture)
// ---------------------------------------------------------------------------
__global__ void zero_bins(int* __restrict__ bc) { bc[threadIdx.x] = 0; }

// ---------------------------------------------------------------------------
// Kernel 1: bin samples by (batch, row-group).  g chosen so that the sample's
// full 4-row stencil [ylo0, yhi1] lies inside rows [4g, 4g+8).
// Atomic order varies run-to-run but only permutes the bin list; each
// sample's final values are order-independent (written to its own slot).
// ---------------------------------------------------------------------------
__global__ __launch_bounds__(256) void binprep(
    const float* __restrict__ ub, const float* __restrict__ noise,
    int* __restrict__ bc, int* __restrict__ bs)
{
    const int n = blockIdx.x * 256 + threadIdx.x;   // 0..BN-1
    const float xsy = ub[2 * n + 1] + noise[2 * n + 1];
    float y = fminf(fmaxf(xsy, 0.0f), (float)(Hq - 1));
    int y0 = (int)floorf(y); y0 = min(max(y0, 0), Hq - 2);
    const int g = (y0 == 0) ? 0 : ((y0 - 1) >> 2);  // 0..31
    const int bin = (n >> 10) * NGRP + g;
    const int idx = atomicAdd(&bc[bin], 1);
    if (idx < BIN_CAP) bs[bin * BIN_CAP + idx] = n;
}

// ---------------------------------------------------------------------------
// Kernel 2: binned Gauss-Newton partials.
// Block = (bin, channel-chunk).  Stage 8 rows x 256 px x 8 ch (64KB payload,
// 73.7KB LDS with pad-9) -- each (b,c,row) read is 1KB contiguous.  Then
// 8-lane groups (one channel each) process the bin's samples from LDS and
// write 5 partials per (chunk, sample).  No big global writes anywhere.
// ---------------------------------------------------------------------------
__global__ __launch_bounds__(512) void gn_binned(
    const float* __restrict__ fb,
    const float* __restrict__ f_t,
    const float* __restrict__ ub,
    const float* __restrict__ noise,
    const int* __restrict__ bc,
    const int* __restrict__ bs,
    float* __restrict__ pH)
{
    __shared__ float tile[8 * 256 * 9];          // [row i][px][c] pad-9
    const int blk  = blockIdx.x;
    const int bin  = blk >> 4;                   // 0..255
    const int chunk = blk & 15;                  // 0..15
    const int b = bin >> 5;
    const int g = bin & 31;
    const int t = threadIdx.x;

    // ---- stage: 64 channel-rows (8 rows x 8 ch), 4 threads... (8 thr/row) --
    {
        const int cr = t >> 3;                   // 0..63
        const int i  = cr >> 3;                  // staged row slot 0..7
        const int c  = cr & 7;                   // channel within chunk
        const int fq = t & 7;                    // f4 phase within the 1KB row
        const int row = min(4 * g + i, Hq - 1);  // clamp (g=31 tail, unread)
        const float* src = fb +
            (((size_t)b * Cq + chunk * CCH + c) * Hq + row) * Wq;
        #pragma unroll
        for (int k = 0; k < 8; ++k) {
            const int f4 = fq + 8 * k;           // 0..63 -> px 4*f4
            const float4 v = *(const float4*)(src + 4 * f4);
            const int px = 4 * f4;
            tile[(i * 256 + px + 0) * 9 + c] = v.x;
            tile[(i * 256 + px + 1) * 9 + c] = v.y;
            tile[(i * 256 + px + 2) * 9 + c] = v.z;
            tile[(i * 256 + px + 3) * 9 + c] = v.w;
        }
    }
    __syncthreads();

    // ---- gather: 64 groups of 8 lanes; group -> sample, lane -> channel ----
    const int nb = bc[bin];
    const int group = t >> 3;
    const int lc = t & 7;                        // channel lane
    const int ch = chunk * CCH + lc;             // global channel

    for (int s = group; s < nb; s += 64) {
        const int n = bs[bin * BIN_CAP + s];

        const float xsx = ub[2 * n]     + noise[2 * n];
        const float xsy = ub[2 * n + 1] + noise[2 * n + 1];

        float x = fminf(fmaxf(xsx, 0.0f), (float)(Wq - 1));
        float y = fminf(fmaxf(xsy, 0.0f), (float)(Hq - 1));
        int x0 = (int)floorf(x); x0 = min(max(x0, 0), Wq - 2);
        int y0 = (int)floorf(y); y0 = min(max(y0, 0), Hq - 2);
        const int x1 = x0 + 1, y1 = y0 + 1;
        const float wx = x - (float)x0;
        const float wy = y - (float)y0;

        const int xlo0 = max(x0 - 1, 0);
        const int xhi1 = min(x1 + 1, Wq - 1);
        const int ylo0 = max(y0 - 1, 0);
        const int yhi1 = min(y1 + 1, Hq - 1);
        const float sx0 = 1.0f / (float)(x1 - xlo0);
        const float sx1 = 1.0f / (float)(xhi1 - x0);
        const float sy0 = 1.0f / (float)(y1 - ylo0);
        const float sy1 = 1.0f / (float)(yhi1 - y0);

        // LDS row slots (guaranteed in [0,8) by binning)
        const int ilo = ylo0 - 4 * g;
        const int i0  = y0   - 4 * g;
        const int i1  = i0 + 1;
        const int ihi = yhi1 - 4 * g;

        #define LD(ii, xx) tile[((ii) * 256 + (xx)) * 9 + lc]
        const float f_lo0 = LD(ilo, x0), f_lo1 = LD(ilo, x1);
        const float f0m = LD(i0, xlo0), f00 = LD(i0, x0);
        const float f01 = LD(i0, x1),   f0p = LD(i0, xhi1);
        const float f1m = LD(i1, xlo0), f10 = LD(i1, x0);
        const float f11 = LD(i1, x1),   f1p = LD(i1, xhi1);
        const float f_hi0 = LD(ihi, x0), f_hi1 = LD(ihi, x1);
        #undef LD

        const float gx00 = (f01 - f0m) * sx0;
        const float gx01 = (f0p - f00) * sx1;
        const float gx10 = (f11 - f1m) * sx0;
        const float gx11 = (f1p - f10) * sx1;
        const float gy00 = (f10 - f_lo0) * sy0;
        const float gy01 = (f11 - f_lo1) * sy0;
        const float gy10 = (f_hi0 - f00) * sy1;
        const float gy11 = (f_hi1 - f01) * sy1;

        const float w00 = (1.0f - wx) * (1.0f - wy);
        const float w01 = wx * (1.0f - wy);
        const float w10 = (1.0f - wx) * wy;
        const float w11 = wx * wy;

        const float fs = f00 * w00 + f01 * w01 + f10 * w10 + f11 * w11;
        const float Jx = gx00 * w00 + gx01 * w01 + gx10 * w10 + gx11 * w11;
        const float Jy = gy00 * w00 + gy01 * w01 + gy10 * w10 + gy11 * w11;
        const float r  = fs - f_t[(size_t)n * Cq + ch];

        float hxx = Jx * Jx;
        float hxy = Jx * Jy;
        float hyy = Jy * Jy;
        float bx  = Jx * r;
        float by  = Jy * r;

        // reduce over the 8-lane group (offsets < 8 stay in the group)
        #pragma unroll
        for (int off = 1; off < 8; off <<= 1) {
            hxx += __shfl_xor(hxx, off);
            hxy += __shfl_xor(hxy, off);
            hyy += __shfl_xor(hyy, off);
            bx  += __shfl_xor(bx, off);
            by  += __shfl_xor(by, off);
        }
        if (lc == 0) {
            float* o = pH + ((size_t)chunk * BN + n) * 5;
            o[0] = hxx; o[1] = hxy; o[2] = hyy; o[3] = bx; o[4] = by;
        }
    }
}

// ---------------------------------------------------------------------------
// Kernel 3: per-sample finalize -- sum the 16 chunk partials (fixed order,
// deterministic), do the 2x2 GN solve, emit e1 contribution and log(det).
// ---------------------------------------------------------------------------
__global__ __launch_bounds__(256) void gn_finalA(
    const float* __restrict__ pH,
    const float* __restrict__ ub, const float* __restrict__ noise,
    float* __restrict__ p2)
{
    const int n = blockIdx.x * 256 + threadIdx.x;   // 0..BN-1
    float hxx = 0.0f, hxy = 0.0f, hyy = 0.0f, bx = 0.0f, by = 0.0f;
    #pragma unroll
    for (int k = 0; k < NCHUNK; ++k) {
        const float* o = pH + ((size_t)k * BN + n) * 5;
        hxx += o[0]; hxy += o[1]; hyy += o[2]; bx += o[3]; by += o[4];
    }

    const float ubx = ub[2 * n];
    const float uby = ub[2 * n + 1];
    const float xsx = ubx + noise[2 * n];
    const float xsy = uby + noise[2 * n + 1];

    const float A  = hxx + EPSq;
    const float Bv = hxy;
    const float D  = hyy + EPSq;

    const float det = A * D - Bv * Bv;
    const float inv = 1.0f / det;
    const float hbx = ( D * bx - Bv * by) * inv;
    const float hby = (-Bv * bx + A * by) * inv;
    const float dx = ubx - (xsx - hbx);
    const float dy = uby - (xsy - hby);
    const float quad = A * dx * dx + 2.0f * Bv * dx * dy + D * dy * dy;

    const float detc = fmaxf(det, 1e-16f);
    p2[n]      = 0.5f * quad;
    p2[BN + n] = logf(detc);
}

// ---------------------------------------------------------------------------
// Kernel 4: single-block final reduction -> (e, e1, e2)
// ---------------------------------------------------------------------------
__global__ __launch_bounds__(1024) void gn_reduce_kernel(
    const float* __restrict__ p2, float* __restrict__ out)
{
    float s1 = 0.0f, s2 = 0.0f;
    for (int i = threadIdx.x; i < BN; i += 1024) {
        s1 += p2[i];
        s2 += p2[BN + i];
    }
    #pragma unroll
    for (int off = 32; off > 0; off >>= 1) {
        s1 += __shfl_down(s1, off);
        s2 += __shfl_down(s2, off);
    }
    __shared__ float l1[16], l2[16];
    const int w = threadIdx.x >> 6;
    if ((threadIdx.x & 63) == 0) { l1[w] = s1; l2[w] = s2; }
    __syncthreads();
    if (threadIdx.x == 0) {
        float e1 = 0.0f, sl = 0.0f;
        #pragma unroll
        for (int i = 0; i < 16; ++i) { e1 += l1[i]; sl += l2[i]; }
        const float e2 = (float)BN * LOG_2PI - 0.5f * sl;
        out[0] = e1 + (2.0f / 7.0f) * e2;  // e
        out[1] = e1;
        out[2] = e2;
    }
}

extern "C" void kernel_launch(void* const* d_in, const int* in_sizes, int n_in,
                              void* d_out, int out_size, void* d_ws, size_t ws_size,
                              hipStream_t stream) {
    const float* fb    = (const float*)d_in[0];
    const float* f_t   = (const float*)d_in[1];
    const float* ub    = (const float*)d_in[2];
    const float* noise = (const float*)d_in[3];
    float* out = (float*)d_out;
    int*   wsi = (int*)d_ws;
    float* wsf = (float*)d_ws;

    int*   bc = wsi;                 // 256 ints
    int*   bs = wsi + BS_OFF;        // 256 * 1024 ints
    float* pH = wsf + H_OFF;         // [16][8192][5]
    float* p2 = wsf + P2_OFF;        // [2][8192]

    zero_bins<<<1, NBINS, 0, stream>>>(bc);
    binprep<<<BN / 256, 256, 0, stream>>>(ub, noise, bc, bs);
    gn_binned<<<NBINS * NCHUNK, 512, 0, stream>>>(fb, f_t, ub, noise, bc, bs, pH);
    gn_finalA<<<BN / 256, 256, 0, stream>>>(pH, ub, noise, p2);
    gn_reduce_kernel<<<1, 1024, 0, stream>>>(p2, out);
}